// Round 1
// baseline (40.316 us; speedup 1.0000x reference)
//
#include <hip/hip_runtime.h>
#include <math.h>

// Problem constants (from reference setup_inputs): z_list (P,B,D) fp32
constexpr int P = 64, B = 512, D = 1024;
constexpr int PSPLIT = 4;            // split P across blocks for occupancy
constexpr int PC = P / PSPLIT;       // 16 p's per block
constexpr int K3B = 32;              // blocks in S/T partial-sum kernel
constexpr int BPB = B / K3B;         // 16 b's per K3 block
#define EPS 1e-8f

__device__ inline float wave_reduce_sum(float v) {
#pragma unroll
  for (int off = 1; off < 64; off <<= 1) v += __shfl_xor(v, off);
  return v;
}

__device__ inline float dot4(const float4& a, const float4& b) {
  return a.x * b.x + a.y * b.y + a.z * b.z + a.w * b.w;
}

// K1: one wave per (b, p-chunk). Streams 16 rows of 1024 floats, computes
// per-row norm (wave shuffle reduce), accumulates raw sum and normalized sum.
// zsum_part/u_part layout: [PSPLIT][B][D]
__global__ __launch_bounds__(64) void k1_rowstats(const float* __restrict__ z,
                                                  float* __restrict__ zsum_part,
                                                  float* __restrict__ u_part) {
  const int blk = blockIdx.x;
  const int b = blk >> 2;            // blk / PSPLIT
  const int c = blk & (PSPLIT - 1);
  const int lane = threadIdx.x;      // 0..63

  float4 zs[4], uu[4];
#pragma unroll
  for (int k = 0; k < 4; ++k) {
    zs[k] = make_float4(0.f, 0.f, 0.f, 0.f);
    uu[k] = make_float4(0.f, 0.f, 0.f, 0.f);
  }

  const size_t pstride = (size_t)B * (D / 4);  // float4 stride between p's
  const float4* base = (const float4*)z + ((size_t)(c * PC) * B + b) * (D / 4);

  float4 cur[4];
#pragma unroll
  for (int k = 0; k < 4; ++k) cur[k] = base[k * 64 + lane];

  for (int pp = 0; pp < PC; ++pp) {
    float4 nxt[4];
    if (pp + 1 < PC) {
      const float4* nb = base + (size_t)(pp + 1) * pstride;
#pragma unroll
      for (int k = 0; k < 4; ++k) nxt[k] = nb[k * 64 + lane];
    } else {
#pragma unroll
      for (int k = 0; k < 4; ++k) nxt[k] = cur[k];
    }

    float ss = 0.f;
#pragma unroll
    for (int k = 0; k < 4; ++k) ss += dot4(cur[k], cur[k]);
    ss = wave_reduce_sum(ss);
    const float w = 1.0f / fmaxf(sqrtf(ss), EPS);

#pragma unroll
    for (int k = 0; k < 4; ++k) {
      zs[k].x += cur[k].x; zs[k].y += cur[k].y; zs[k].z += cur[k].z; zs[k].w += cur[k].w;
      uu[k].x += w * cur[k].x; uu[k].y += w * cur[k].y;
      uu[k].z += w * cur[k].z; uu[k].w += w * cur[k].w;
    }
#pragma unroll
    for (int k = 0; k < 4; ++k) cur[k] = nxt[k];
  }

  float4* zp = (float4*)zsum_part + ((size_t)c * B + b) * (D / 4);
  float4* up = (float4*)u_part + ((size_t)c * B + b) * (D / 4);
#pragma unroll
  for (int k = 0; k < 4; ++k) {
    zp[k * 64 + lane] = zs[k];
    up[k * 64 + lane] = uu[k];
  }
}

// K2: one block per b. Combine PSPLIT partials, normalize the mean row into
// an[b], sum U[b], emit diag[b] = U[b]·an[b].
__global__ __launch_bounds__(256) void k2_normalize(const float* __restrict__ zsum_part,
                                                    const float* __restrict__ u_part,
                                                    float* __restrict__ an,
                                                    float* __restrict__ Uv,
                                                    float* __restrict__ diag) {
  const int b = blockIdx.x;
  const int t = threadIdx.x;  // owns float4 index t (d = 4t..4t+3), D/4 == 256
  __shared__ float red[8];

  float4 zs = make_float4(0.f, 0.f, 0.f, 0.f);
  float4 uu = make_float4(0.f, 0.f, 0.f, 0.f);
#pragma unroll
  for (int c = 0; c < PSPLIT; ++c) {
    float4 a = ((const float4*)zsum_part)[((size_t)c * B + b) * (D / 4) + t];
    float4 u = ((const float4*)u_part)[((size_t)c * B + b) * (D / 4) + t];
    zs.x += a.x; zs.y += a.y; zs.z += a.z; zs.w += a.w;
    uu.x += u.x; uu.y += u.y; uu.z += u.z; uu.w += u.w;
  }

  // ||z_sum||^2 across the block, broadcast to all threads
  float ss = dot4(zs, zs);
  ss = wave_reduce_sum(ss);
  const int wid = t >> 6;
  if ((t & 63) == 0) red[wid] = ss;
  __syncthreads();
  ss = red[0] + red[1] + red[2] + red[3];

  // an = (z_sum/P) / max(||z_sum||/P, eps) = z_sum / max(||z_sum||, P*eps)
  const float inv = 1.0f / fmaxf(sqrtf(ss), (float)P * EPS);
  float4 a4 = make_float4(zs.x * inv, zs.y * inv, zs.z * inv, zs.w * inv);

  ((float4*)an)[(size_t)b * (D / 4) + t] = a4;
  ((float4*)Uv)[(size_t)b * (D / 4) + t] = uu;

  float dg = dot4(uu, a4);
  dg = wave_reduce_sum(dg);
  if ((t & 63) == 0) red[4 + wid] = dg;
  __syncthreads();
  if (t == 0) diag[b] = red[4] + red[5] + red[6] + red[7];
}

// K3: partial column-sums of an and Uv over b-chunks -> Spart/Tpart [K3B][D]
__global__ __launch_bounds__(256) void k3_colsum(const float* __restrict__ an,
                                                 const float* __restrict__ Uv,
                                                 float* __restrict__ Spart,
                                                 float* __restrict__ Tpart) {
  const int blk = blockIdx.x;
  const int t = threadIdx.x;
  float4 s = make_float4(0.f, 0.f, 0.f, 0.f);
  float4 tt = make_float4(0.f, 0.f, 0.f, 0.f);
#pragma unroll 4
  for (int i = 0; i < BPB; ++i) {
    const size_t b = (size_t)blk * BPB + i;
    float4 a = ((const float4*)an)[b * (D / 4) + t];
    float4 u = ((const float4*)Uv)[b * (D / 4) + t];
    s.x += a.x; s.y += a.y; s.z += a.z; s.w += a.w;
    tt.x += u.x; tt.y += u.y; tt.z += u.z; tt.w += u.w;
  }
  ((float4*)Spart)[(size_t)blk * (D / 4) + t] = s;
  ((float4*)Tpart)[(size_t)blk * (D / 4) + t] = tt;
}

// K4: final combine. S = sum Spart, T = sum Tpart, out = (S·T - sum diag)/count - 1
__global__ __launch_bounds__(256) void k4_final(const float* __restrict__ Spart,
                                                const float* __restrict__ Tpart,
                                                const float* __restrict__ diag,
                                                float* __restrict__ out) {
  const int t = threadIdx.x;
  __shared__ float red[4];
  float4 S = make_float4(0.f, 0.f, 0.f, 0.f);
  float4 T = make_float4(0.f, 0.f, 0.f, 0.f);
#pragma unroll 4
  for (int blk = 0; blk < K3B; ++blk) {
    float4 s = ((const float4*)Spart)[(size_t)blk * (D / 4) + t];
    float4 u = ((const float4*)Tpart)[(size_t)blk * (D / 4) + t];
    S.x += s.x; S.y += s.y; S.z += s.z; S.w += s.w;
    T.x += u.x; T.y += u.y; T.z += u.z; T.w += u.w;
  }
  float local = dot4(S, T) - diag[t] - diag[t + 256];
  local = wave_reduce_sum(local);
  const int wid = t >> 6;
  if ((t & 63) == 0) red[wid] = local;
  __syncthreads();
  if (t == 0) {
    const float tot = red[0] + red[1] + red[2] + red[3];
    const float count = 64.0f * 512.0f * 511.0f;  // P*B*(B-1), exact in fp32
    out[0] = tot / count - 1.0f;
  }
}

extern "C" void kernel_launch(void* const* d_in, const int* in_sizes, int n_in,
                              void* d_out, int out_size, void* d_ws, size_t ws_size,
                              hipStream_t stream) {
  const float* z = (const float*)d_in[0];  // z_list (P,B,D); d_in[1] unused

  float* ws = (float*)d_ws;
  float* zsum_part = ws;                                      // PSPLIT*B*D
  float* u_part = zsum_part + (size_t)PSPLIT * B * D;         // PSPLIT*B*D
  float* an = u_part + (size_t)PSPLIT * B * D;                // B*D
  float* Uv = an + (size_t)B * D;                             // B*D
  float* diag = Uv + (size_t)B * D;                           // B
  float* Spart = diag + B;                                    // K3B*D
  float* Tpart = Spart + (size_t)K3B * D;                     // K3B*D

  k1_rowstats<<<B * PSPLIT, 64, 0, stream>>>(z, zsum_part, u_part);
  k2_normalize<<<B, 256, 0, stream>>>(zsum_part, u_part, an, Uv, diag);
  k3_colsum<<<K3B, 256, 0, stream>>>(an, Uv, Spart, Tpart);
  k4_final<<<1, 256, 0, stream>>>(Spart, Tpart, diag, (float*)d_out);
}

// Round 2
// 36.109 us; speedup vs baseline: 1.1165x; 1.1165x over previous
//
#include <hip/hip_runtime.h>
#include <math.h>

// Problem constants (from reference setup_inputs): z_list (P,B,D) fp32
constexpr int P = 64, B = 512, D = 1024;
constexpr int D4 = D / 4;           // 256 float4 per row
constexpr int WAVES = 4;            // waves per block in main kernel
constexpr int PC = P / WAVES;       // 16 p's per wave
constexpr int K3B = 32;             // blocks in S/T partial-sum kernel
constexpr int BPB = B / K3B;        // 16 b's per K3 block
#define EPS 1e-8f

__device__ inline float wave_reduce_sum(float v) {
#pragma unroll
  for (int off = 1; off < 64; off <<= 1) v += __shfl_xor(v, off);
  return v;
}

__device__ inline float dot4(const float4& a, const float4& b) {
  return a.x * b.x + a.y * b.y + a.z * b.z + a.w * b.w;
}

// K_main: one block (4 waves) per b. Each wave streams 16 p-rows of z[:,b,:],
// computes per-row norm via wave shuffle-reduce, accumulates raw sum (zs) and
// normalized sum (uu) in registers. LDS combines the 4 waves, then the block
// normalizes the mean row -> an[b], writes U[b], and emits diag[b] = U[b].an[b].
__global__ __launch_bounds__(256) void k_main(const float* __restrict__ z,
                                              float* __restrict__ an,
                                              float* __restrict__ Uv,
                                              float* __restrict__ diag) {
  const int b = blockIdx.x;
  const int t = threadIdx.x;
  const int w = t >> 6;              // wave 0..3
  const int lane = t & 63;

  __shared__ float4 lds_zs[WAVES][D4];  // 16 KB
  __shared__ float4 lds_uu[WAVES][D4];  // 16 KB
  __shared__ float red[2 * WAVES];

  float4 zs[4], uu[4];
#pragma unroll
  for (int k = 0; k < 4; ++k) {
    zs[k] = make_float4(0.f, 0.f, 0.f, 0.f);
    uu[k] = make_float4(0.f, 0.f, 0.f, 0.f);
  }

  // wave w handles p = w*PC .. w*PC+PC-1, row z[p][b][:]
  const size_t pstride = (size_t)B * D4;  // float4 stride between p's
  const float4* base = (const float4*)z + ((size_t)(w * PC) * B + b) * D4;

  float4 cur[4];
#pragma unroll
  for (int k = 0; k < 4; ++k) cur[k] = base[k * 64 + lane];

  for (int pp = 0; pp < PC; ++pp) {
    float4 nxt[4];
    if (pp + 1 < PC) {
      const float4* nb = base + (size_t)(pp + 1) * pstride;
#pragma unroll
      for (int k = 0; k < 4; ++k) nxt[k] = nb[k * 64 + lane];
    } else {
#pragma unroll
      for (int k = 0; k < 4; ++k) nxt[k] = cur[k];
    }

    float ss = 0.f;
#pragma unroll
    for (int k = 0; k < 4; ++k) ss += dot4(cur[k], cur[k]);
    ss = wave_reduce_sum(ss);
    const float wgt = 1.0f / fmaxf(sqrtf(ss), EPS);

#pragma unroll
    for (int k = 0; k < 4; ++k) {
      zs[k].x += cur[k].x; zs[k].y += cur[k].y; zs[k].z += cur[k].z; zs[k].w += cur[k].w;
      uu[k].x += wgt * cur[k].x; uu[k].y += wgt * cur[k].y;
      uu[k].z += wgt * cur[k].z; uu[k].w += wgt * cur[k].w;
    }
#pragma unroll
    for (int k = 0; k < 4; ++k) cur[k] = nxt[k];
  }

  // cross-wave combine: wave w's float4 index k*64+lane
#pragma unroll
  for (int k = 0; k < 4; ++k) {
    lds_zs[w][k * 64 + lane] = zs[k];
    lds_uu[w][k * 64 + lane] = uu[k];
  }
  __syncthreads();

  // thread t now owns float4 index t (d = 4t..4t+3)
  float4 zsum = make_float4(0.f, 0.f, 0.f, 0.f);
  float4 usum = make_float4(0.f, 0.f, 0.f, 0.f);
#pragma unroll
  for (int ww = 0; ww < WAVES; ++ww) {
    float4 a = lds_zs[ww][t];
    float4 u = lds_uu[ww][t];
    zsum.x += a.x; zsum.y += a.y; zsum.z += a.z; zsum.w += a.w;
    usum.x += u.x; usum.y += u.y; usum.z += u.z; usum.w += u.w;
  }

  // ||z_sum||^2 across the block, broadcast
  float ss = dot4(zsum, zsum);
  ss = wave_reduce_sum(ss);
  if (lane == 0) red[w] = ss;
  __syncthreads();
  ss = red[0] + red[1] + red[2] + red[3];

  // an = (z_sum/P)/max(||z_sum||/P, eps) = z_sum / max(||z_sum||, P*eps)
  const float inv = 1.0f / fmaxf(sqrtf(ss), (float)P * EPS);
  float4 a4 = make_float4(zsum.x * inv, zsum.y * inv, zsum.z * inv, zsum.w * inv);

  ((float4*)an)[(size_t)b * D4 + t] = a4;
  ((float4*)Uv)[(size_t)b * D4 + t] = usum;

  float dg = dot4(usum, a4);
  dg = wave_reduce_sum(dg);
  if (lane == 0) red[WAVES + w] = dg;
  __syncthreads();
  if (t == 0) diag[b] = red[WAVES] + red[WAVES + 1] + red[WAVES + 2] + red[WAVES + 3];
}

// K3: partial column-sums of an and Uv over b-chunks -> Spart/Tpart [K3B][D]
__global__ __launch_bounds__(256) void k3_colsum(const float* __restrict__ an,
                                                 const float* __restrict__ Uv,
                                                 float* __restrict__ Spart,
                                                 float* __restrict__ Tpart) {
  const int blk = blockIdx.x;
  const int t = threadIdx.x;
  float4 s = make_float4(0.f, 0.f, 0.f, 0.f);
  float4 tt = make_float4(0.f, 0.f, 0.f, 0.f);
#pragma unroll 4
  for (int i = 0; i < BPB; ++i) {
    const size_t b = (size_t)blk * BPB + i;
    float4 a = ((const float4*)an)[b * D4 + t];
    float4 u = ((const float4*)Uv)[b * D4 + t];
    s.x += a.x; s.y += a.y; s.z += a.z; s.w += a.w;
    tt.x += u.x; tt.y += u.y; tt.z += u.z; tt.w += u.w;
  }
  ((float4*)Spart)[(size_t)blk * D4 + t] = s;
  ((float4*)Tpart)[(size_t)blk * D4 + t] = tt;
}

// K4: final combine. S = sum Spart, T = sum Tpart, out = (S.T - sum diag)/count - 1
__global__ __launch_bounds__(256) void k4_final(const float* __restrict__ Spart,
                                                const float* __restrict__ Tpart,
                                                const float* __restrict__ diag,
                                                float* __restrict__ out) {
  const int t = threadIdx.x;
  __shared__ float red[4];
  float4 S = make_float4(0.f, 0.f, 0.f, 0.f);
  float4 T = make_float4(0.f, 0.f, 0.f, 0.f);
#pragma unroll 4
  for (int blk = 0; blk < K3B; ++blk) {
    float4 s = ((const float4*)Spart)[(size_t)blk * D4 + t];
    float4 u = ((const float4*)Tpart)[(size_t)blk * D4 + t];
    S.x += s.x; S.y += s.y; S.z += s.z; S.w += s.w;
    T.x += u.x; T.y += u.y; T.z += u.z; T.w += u.w;
  }
  float local = dot4(S, T) - diag[t] - diag[t + 256];
  local = wave_reduce_sum(local);
  const int wid = t >> 6;
  if ((t & 63) == 0) red[wid] = local;
  __syncthreads();
  if (t == 0) {
    const float tot = red[0] + red[1] + red[2] + red[3];
    const float count = 64.0f * 512.0f * 511.0f;  // P*B*(B-1), exact in fp32
    out[0] = tot / count - 1.0f;
  }
}

extern "C" void kernel_launch(void* const* d_in, const int* in_sizes, int n_in,
                              void* d_out, int out_size, void* d_ws, size_t ws_size,
                              hipStream_t stream) {
  const float* z = (const float*)d_in[0];  // z_list (P,B,D); d_in[1] unused

  float* ws = (float*)d_ws;
  float* an = ws;                                  // B*D
  float* Uv = an + (size_t)B * D;                  // B*D
  float* diag = Uv + (size_t)B * D;                // B
  float* Spart = diag + B;                         // K3B*D
  float* Tpart = Spart + (size_t)K3B * D;          // K3B*D

  k_main<<<B, 256, 0, stream>>>(z, an, Uv, diag);
  k3_colsum<<<K3B, 256, 0, stream>>>(an, Uv, Spart, Tpart);
  k4_final<<<1, 256, 0, stream>>>(Spart, Tpart, diag, (float*)d_out);
}